// Round 14
// baseline (253.213 us; speedup 1.0000x reference)
//
#include <hip/hip_runtime.h>
#include <hip/hip_bf16.h>

#define NN 100000
#define NE 1600000
#define NG 64
#define NBUK 782   // cdiv(NN,128)
#define NPERM (NBUK * 128)  // 100096
#define ABLK 512   // binning blocks
#define ACH 3125   // edges per binning block (512*3125 = 1.6M)
#define PSPLIT 8   // pool parts per graph

typedef short short8 __attribute__((ext_vector_type(8)));
typedef float f32x4 __attribute__((ext_vector_type(4)));
typedef float f32x2 __attribute__((ext_vector_type(2)));
typedef unsigned short ushort8v __attribute__((ext_vector_type(8)));
typedef unsigned int uint4v __attribute__((ext_vector_type(4)));
typedef unsigned int uint2v __attribute__((ext_vector_type(2)));

static inline int cdiv(int a, int b) { return (a + b - 1) / b; }

__device__ __forceinline__ short f2bf(float f) {
    return __builtin_bit_cast(short, __float2bfloat16(f));
}
__device__ __forceinline__ float bf2f(unsigned short u) {
    unsigned int x = ((unsigned int)u) << 16;
    return __builtin_bit_cast(float, x);
}

// ---- fused histA + setup (xcvt, wt0/1/2, gbound) -----------------------
__device__ __forceinline__ void wt_body(const float* Wl, const float* Wr, short* WT,
                                        int OUT, int idx) {
    int c = idx >> 7, k = idx & 127;
    float v = (c < OUT) ? Wl[k * OUT + c] : Wr[k * OUT + (c - OUT)];
    WT[idx] = f2bf(v);
}

__global__ __launch_bounds__(256) void hist_setup_kernel(
    const int* __restrict__ dst, int* __restrict__ blockHist,
    const float* __restrict__ x, short* __restrict__ xb,
    const float* __restrict__ Wl0, const float* __restrict__ Wr0, short* __restrict__ WT0,
    const float* __restrict__ Wl1, const float* __restrict__ Wr1, short* __restrict__ WT1,
    const float* __restrict__ Wl2, const float* __restrict__ Wr2, short* __restrict__ WT2,
    const int* __restrict__ batch, int* __restrict__ gstart, int E) {
    __shared__ int h[NBUK];
    int b = blockIdx.x;
    int tid = threadIdx.x;
    if (b < ABLK) {
        for (int i = tid; i < NBUK; i += 256) h[i] = 0;
        __syncthreads();
        int base = b * ACH;
        int end = min(base + ACH, E);
        for (int e = base + tid; e < end; e += 256) atomicAdd(&h[dst[e] >> 7], 1);
        __syncthreads();
        for (int i = tid; i < NBUK; i += 256) blockHist[(size_t)i * ABLK + b] = h[i];
    } else if (b < ABLK + 6250) {
        int i = (b - ABLK) * 256 + tid;  // n8 = 1,600,000
        const float4 v0 = ((const float4*)x)[i * 2];
        const float4 v1 = ((const float4*)x)[i * 2 + 1];
        short8 o;
        o[0] = f2bf(v0.x); o[1] = f2bf(v0.y); o[2] = f2bf(v0.z); o[3] = f2bf(v0.w);
        o[4] = f2bf(v1.x); o[5] = f2bf(v1.y); o[6] = f2bf(v1.z); o[7] = f2bf(v1.w);
        ((short8*)xb)[i] = o;
    } else if (b < ABLK + 6378) {
        wt_body(Wl0, Wr0, WT0, 128, (b - ABLK - 6250) * 256 + tid);
    } else if (b < ABLK + 6506) {
        wt_body(Wl1, Wr1, WT1, 128, (b - ABLK - 6378) * 256 + tid);
    } else if (b < ABLK + 6570) {
        wt_body(Wl2, Wr2, WT2, 64, (b - ABLK - 6506) * 256 + tid);
    } else {
        int n = (b - ABLK - 6570) * 256 + tid;
        if (n >= NN) return;
        int g1 = batch[n];
        if (n == 0) {
            for (int g = 0; g <= g1; ++g) gstart[g] = 0;
        } else {
            int pb = batch[n - 1];
            for (int g = pb + 1; g <= g1; ++g) gstart[g] = n;
        }
        if (n == NN - 1) {
            for (int g = g1 + 1; g <= NG; ++g) gstart[g] = NN;
        }
    }
}

__global__ __launch_bounds__(512) void scanBlk_kernel(int* __restrict__ blockHist,
                                                      int* __restrict__ bucketTot) {
    __shared__ int s[ABLK];
    int b = blockIdx.x, t = threadIdx.x;
    int v = blockHist[(size_t)b * ABLK + t];
    s[t] = v;
    __syncthreads();
    for (int o = 1; o < ABLK; o <<= 1) {
        int u = (t >= o) ? s[t - o] : 0;
        __syncthreads();
        s[t] += u;
        __syncthreads();
    }
    blockHist[(size_t)b * ABLK + t] = s[t] - v;
    if (t == ABLK - 1) bucketTot[b] = s[ABLK - 1];
}

__global__ __launch_bounds__(1024) void scanTot_kernel(const int* __restrict__ bucketTot,
                                                       int* __restrict__ bucketBase,
                                                       int* __restrict__ off, int E) {
    __shared__ int s[1024];
    int t = threadIdx.x;
    int v = (t < NBUK) ? bucketTot[t] : 0;
    s[t] = v;
    __syncthreads();
    for (int o = 1; o < 1024; o <<= 1) {
        int u = (t >= o) ? s[t - o] : 0;
        __syncthreads();
        s[t] += u;
        __syncthreads();
    }
    if (t < NBUK) bucketBase[t] = s[t] - v;
    if (t == 0) {
        bucketBase[NBUK] = E;
        off[NN] = E;
    }
}

__global__ __launch_bounds__(256) void binA_kernel(const int* __restrict__ src,
                                                   const int* __restrict__ dst,
                                                   const int* __restrict__ blockHist,
                                                   const int* __restrict__ bucketBase,
                                                   int* __restrict__ binned, int E) {
    __shared__ int cur[NBUK];
    __shared__ int lbase[NBUK];
    for (int i = threadIdx.x; i < NBUK; i += 256) {
        cur[i] = 0;
        lbase[i] = bucketBase[i] + blockHist[(size_t)i * ABLK + blockIdx.x];
    }
    __syncthreads();
    int base = blockIdx.x * ACH;
    int end = min(base + ACH, E);
    for (int e = base + threadIdx.x; e < end; e += 256) {
        int d = dst[e];
        int b = d >> 7;
        int r = atomicAdd(&cur[b], 1);
        binned[lbase[b] + r] = src[e] | ((d & 127) << 20);
    }
}

// per bucket: single LDS pass -> deg/off/ideg + local counting sort ->
// coalesced csr flush + degree-sorted perm segment (stable, deterministic).
__global__ __launch_bounds__(256) void bucketB_kernel(const int* __restrict__ binned,
                                                      const int* __restrict__ bucketBase,
                                                      int* __restrict__ csr,
                                                      int* __restrict__ off,
                                                      float* __restrict__ ideg,
                                                      int* __restrict__ perm, int N) {
    __shared__ int pair[4096];
    __shared__ int stage[4096];
    __shared__ int deg[128], loff[128], cur[128];
    __shared__ int dkey[128];
    int b = blockIdx.x, t = threadIdx.x;
    int e0 = bucketBase[b], e1 = bucketBase[b + 1];
    int cnt = e1 - e0;
    bool fits = (cnt <= 4096);
    if (t < 128) deg[t] = 0;
    __syncthreads();
    if (fits) {
        for (int i = t; i < cnt; i += 256) pair[i] = binned[e0 + i];
        __syncthreads();
        for (int i = t; i < cnt; i += 256) atomicAdd(&deg[pair[i] >> 20], 1);
    } else {
        for (int i = t; i < cnt; i += 256) atomicAdd(&deg[binned[e0 + i] >> 20], 1);
    }
    __syncthreads();
    if (t < 128) loff[t] = deg[t];
    __syncthreads();
    for (int o = 1; o < 128; o <<= 1) {
        int u = (t < 128 && t >= o) ? loff[t - o] : 0;
        __syncthreads();
        if (t < 128) loff[t] += u;
        __syncthreads();
    }
    int nodeBase = b * 128;
    if (t < 128) {
        int ex = loff[t] - deg[t];
        cur[t] = ex;
        int n = nodeBase + t;
        if (n < N) {
            off[n] = e0 + ex;
            ideg[n] = 1.0f / (float)max(deg[t], 1);
        }
        dkey[t] = (n < N) ? deg[t] : 0x7fff;  // invalid nodes sort last
    }
    __syncthreads();
    // stable rank-by-degree over the 128-node window -> perm segment
    if (t < 128) {
        int d = dkey[t];
        int rk = 0;
        for (int u = 0; u < 128; ++u) {
            int du = dkey[u];
            rk += (du < d) || (du == d && u < t);
        }
        perm[nodeBase + rk] = nodeBase + t;
    }
    if (fits) {
        for (int i = t; i < cnt; i += 256) {
            int p = pair[i];
            int r = atomicAdd(&cur[p >> 20], 1);
            stage[r] = p & 0xFFFFF;
        }
        __syncthreads();
        for (int i = t; i < cnt; i += 256) csr[e0 + i] = stage[i];
    } else {
        for (int i = t; i < cnt; i += 256) {
            int p = binned[e0 + i];
            int r = atomicAdd(&cur[p >> 20], 1);
            csr[e0 + r] = p & 0xFFFFF;
        }
    }
}

// ---- MFMA dual GEMM: P(fp8) = h@Wl, Q(bf16) = h@Wr + b -----------------
template <int OUT>
__global__ __launch_bounds__(256) void sage_gemm_mfma(
    const short* __restrict__ h, const short* __restrict__ WT,
    const float* __restrict__ bias,
    unsigned char* __restrict__ P, short* __restrict__ Q, int N) {
    constexpr int K = 128;
    constexpr int NT = OUT / 32;       // 16-col tiles per wave
    constexpr int WC = OUT / 2;        // cols per wave (64 or 32)
    constexpr int PWP = WC / 4 + 4;    // P LDS pitch in words
    constexpr int PWQ = WC / 2 + 4;    // Q LDS pitch in words
    constexpr int LDSB = 32 * PWQ * 4; // per-wave epilogue LDS bytes

    __shared__ char As[16384];         // 64 rows x 128 bf16, swizzled
    __shared__ char eLds[4 * LDSB];

    const int tid = threadIdx.x;
    const int w = tid >> 6;
    const int lane = tid & 63;
    const int l15 = lane & 15;
    const int lhi = lane >> 4;
    const int rowBase = blockIdx.x * 64;
    const int colBase = w * WC;            // WT row base
    const bool isQ = (w >= 2);
    const int ocolBase = isQ ? colBase - OUT : colBase;
    char* myL = eLds + w * LDSB;

    // stage A tile: dest linear, source inverse-XOR-swizzled so
    // LDS[row][col ^ ((row&7)<<4)] = G[row][col].
    {
        const char* gsrc = (const char*)(h + (size_t)rowBase * K);
#pragma unroll
        for (int p = 0; p < 4; ++p) {
            int lbase = (w * 4 + p) * 1024;
            int loff = lbase + lane * 16;
            int row = loff >> 8;
            int scol = (loff & 255) ^ ((row & 7) << 4);
            __builtin_amdgcn_global_load_lds(
                (const __attribute__((address_space(1))) unsigned int*)(gsrc + (size_t)row * 256 + scol),
                (__attribute__((address_space(3))) unsigned int*)(As + lbase),
                16, 0, 0);
        }
    }
    __syncthreads();

    f32x4 acc[4][NT];
#pragma unroll
    for (int mt = 0; mt < 4; ++mt)
#pragma unroll
        for (int nt = 0; nt < NT; ++nt) acc[mt][nt] = (f32x4){0.f, 0.f, 0.f, 0.f};

#pragma unroll
    for (int kt = 0; kt < 4; ++kt) {
        const int kb = kt * 64 + lhi * 16;  // byte offset within row
        short8 a[4], b[NT];
#pragma unroll
        for (int mt = 0; mt < 4; ++mt) {
            int row = mt * 16 + l15;
            a[mt] = *(const short8*)(As + row * 256 + (kb ^ ((row & 7) << 4)));
        }
#pragma unroll
        for (int nt = 0; nt < NT; ++nt)
            b[nt] = *(const short8*)(WT + (size_t)(colBase + nt * 16 + l15) * K + kt * 32 + lhi * 8);
        // swapped operands -> transposed output tile
#pragma unroll
        for (int mt = 0; mt < 4; ++mt)
#pragma unroll
            for (int nt = 0; nt < NT; ++nt)
                acc[mt][nt] = __builtin_amdgcn_mfma_f32_16x16x32_bf16(b[nt], a[mt], acc[mt][nt], 0, 0, 0);
    }

    if (!isQ) {
        // P: pack 4 fp8 per (mt,nt) -> LDS -> coalesced dwordx4 stores
        constexpr int LPR = WC / 16;
        constexpr int RPP = 64 / LPR;
        constexpr int NP = 32 / RPP;
#pragma unroll
        for (int hh = 0; hh < 2; ++hh) {
#pragma unroll
            for (int mt2 = 0; mt2 < 2; ++mt2) {
                int mt = hh * 2 + mt2;
                int lr = mt2 * 16 + l15;
#pragma unroll
                for (int nt = 0; nt < NT; ++nt) {
                    unsigned u = (unsigned)__builtin_amdgcn_cvt_pk_fp8_f32(
                        acc[mt][nt][0], acc[mt][nt][1], 0, false);
                    u = (unsigned)__builtin_amdgcn_cvt_pk_fp8_f32(
                        acc[mt][nt][2], acc[mt][nt][3], (int)u, true);
                    *(unsigned*)(myL + (size_t)(lr * PWP + nt * 4 + lhi) * 4) = u;
                }
            }
#pragma unroll
            for (int p2 = 0; p2 < NP; ++p2) {
                int lr = p2 * RPP + lane / LPR;
                int wc = (lane % LPR) * 4;
                uint4v v = *(uint4v*)(myL + (size_t)(lr * PWP + wc) * 4);
                int grow = rowBase + hh * 32 + lr;
                if (grow < N)
                    *(uint4v*)(P + (size_t)grow * OUT + ocolBase + wc * 4) = v;
            }
        }
    } else {
        // Q: +bias, pack 4 bf16 (8B) per (mt,nt) -> LDS -> dwordx4 stores
        float4 bj[NT];
#pragma unroll
        for (int nt = 0; nt < NT; ++nt)
            bj[nt] = *(const float4*)(bias + ocolBase + nt * 16 + lhi * 4);
        constexpr int LPR = WC / 8;
        constexpr int RPP = 64 / LPR;
        constexpr int NP = 32 / RPP;
#pragma unroll
        for (int hh = 0; hh < 2; ++hh) {
#pragma unroll
            for (int mt2 = 0; mt2 < 2; ++mt2) {
                int mt = hh * 2 + mt2;
                int lr = mt2 * 16 + l15;
#pragma unroll
                for (int nt = 0; nt < NT; ++nt) {
                    float v0 = acc[mt][nt][0] + bj[nt].x;
                    float v1 = acc[mt][nt][1] + bj[nt].y;
                    float v2 = acc[mt][nt][2] + bj[nt].z;
                    float v3 = acc[mt][nt][3] + bj[nt].w;
                    unsigned lo = ((unsigned)(unsigned short)f2bf(v0)) |
                                  ((unsigned)(unsigned short)f2bf(v1) << 16);
                    unsigned hi = ((unsigned)(unsigned short)f2bf(v2)) |
                                  ((unsigned)(unsigned short)f2bf(v3) << 16);
                    uint2v u; u[0] = lo; u[1] = hi;
                    *(uint2v*)(myL + (size_t)(lr * PWQ + (nt * 4 + lhi) * 2) * 4) = u;
                }
            }
#pragma unroll
            for (int p2 = 0; p2 < NP; ++p2) {
                int lr = p2 * RPP + lane / LPR;
                int wc = (lane % LPR) * 4;
                uint4v v = *(uint4v*)(myL + (size_t)(lr * PWQ + wc) * 4);
                int grow = rowBase + hh * 32 + lr;
                if (grow < N)
                    *(uint4v*)((unsigned short*)Q + (size_t)grow * OUT + ocolBase + (lane % LPR) * 8) = v;
            }
        }
    }
}

// ---- CSR gather (degree-sorted schedule): hout[n] = relu?(Q[n]+ideg*sum P[src])
template <int F, bool RELU>
__global__ __launch_bounds__(256) void gather_kernel(
    const int* __restrict__ csr, const int* __restrict__ off,
    const unsigned char* __restrict__ P, const float* __restrict__ ideg,
    const short* __restrict__ Qin, short* __restrict__ hout,
    const int* __restrict__ perm, int N) {
    constexpr int C = F / 16;  // threads per node row
    int t = blockIdx.x * blockDim.x + threadIdx.x;
    int pidx = t / C, c = t % C;
    if (pidx >= NPERM) return;
    int n = perm[pidx];
    if (n >= N) return;
    int e0 = off[n], e1 = off[n + 1];
    const size_t cb = (size_t)c * 16;

    float f[16];
#pragma unroll
    for (int j = 0; j < 16; ++j) f[j] = 0.f;

    int e = e0;
    for (; e + 4 <= e1; e += 4) {
        int s0 = csr[e + 0], s1 = csr[e + 1], s2 = csr[e + 2], s3 = csr[e + 3];
        uint4v u0 = *(const uint4v*)(P + (size_t)s0 * F + cb);
        uint4v u1 = *(const uint4v*)(P + (size_t)s1 * F + cb);
        uint4v u2 = *(const uint4v*)(P + (size_t)s2 * F + cb);
        uint4v u3 = *(const uint4v*)(P + (size_t)s3 * F + cb);
#pragma unroll
        for (int wd = 0; wd < 4; ++wd) {
            f32x2 a0 = __builtin_amdgcn_cvt_pk_f32_fp8(u0[wd], false);
            f32x2 b0 = __builtin_amdgcn_cvt_pk_f32_fp8(u0[wd], true);
            f32x2 a1 = __builtin_amdgcn_cvt_pk_f32_fp8(u1[wd], false);
            f32x2 b1 = __builtin_amdgcn_cvt_pk_f32_fp8(u1[wd], true);
            f32x2 a2 = __builtin_amdgcn_cvt_pk_f32_fp8(u2[wd], false);
            f32x2 b2 = __builtin_amdgcn_cvt_pk_f32_fp8(u2[wd], true);
            f32x2 a3 = __builtin_amdgcn_cvt_pk_f32_fp8(u3[wd], false);
            f32x2 b3 = __builtin_amdgcn_cvt_pk_f32_fp8(u3[wd], true);
            f[wd * 4 + 0] += (a0[0] + a1[0]) + (a2[0] + a3[0]);
            f[wd * 4 + 1] += (a0[1] + a1[1]) + (a2[1] + a3[1]);
            f[wd * 4 + 2] += (b0[0] + b1[0]) + (b2[0] + b3[0]);
            f[wd * 4 + 3] += (b0[1] + b1[1]) + (b2[1] + b3[1]);
        }
    }
    for (; e < e1; ++e) {
        uint4v u = *(const uint4v*)(P + (size_t)csr[e] * F + cb);
#pragma unroll
        for (int wd = 0; wd < 4; ++wd) {
            f32x2 a = __builtin_amdgcn_cvt_pk_f32_fp8(u[wd], false);
            f32x2 b = __builtin_amdgcn_cvt_pk_f32_fp8(u[wd], true);
            f[wd * 4 + 0] += a[0];
            f[wd * 4 + 1] += a[1];
            f[wd * 4 + 2] += b[0];
            f[wd * 4 + 3] += b[1];
        }
    }

    float sc = ideg[n];
    const short* qp = Qin + (size_t)n * F + cb;
    ushort8v qa = *(const ushort8v*)qp, qb = *(const ushort8v*)(qp + 8);
    short8 oa, ob;
#pragma unroll
    for (int j = 0; j < 8; ++j) {
        float va = fmaf(f[j], sc, bf2f(qa[j]));
        float vb = fmaf(f[j + 8], sc, bf2f(qb[j]));
        if (RELU) { va = fmaxf(va, 0.f); vb = fmaxf(vb, 0.f); }
        oa[j] = f2bf(va);
        ob[j] = f2bf(vb);
    }
    short* op = hout + (size_t)n * F + cb;
    *(short8*)op = oa;
    *(short8*)(op + 8) = ob;
}

// ---- segmented mean pool: 8 parts per graph, no atomics -----------------
__global__ __launch_bounds__(256) void pool2_kernel(const unsigned short* __restrict__ h,
                                                    const int* __restrict__ gstart,
                                                    float* __restrict__ gpart) {
    int g = blockIdx.x / PSPLIT, part = blockIdx.x % PSPLIT;
    int s = gstart[g], e = gstart[g + 1];
    int cnt = e - s;
    int chunk = (cnt + PSPLIT - 1) / PSPLIT;
    int n0 = s + part * chunk;
    int n1 = min(n0 + chunk, e);
    int j = threadIdx.x & 63;
    int r = threadIdx.x >> 6;  // 4 row lanes
    float acc = 0.f;
    for (int n = n0 + r; n < n1; n += 4) acc += bf2f(h[(size_t)n * 64 + j]);
    __shared__ float ls[256];
    ls[threadIdx.x] = acc;
    __syncthreads();
    if (threadIdx.x < 64) {
        float v = ls[threadIdx.x] + ls[threadIdx.x + 64] + ls[threadIdx.x + 128] + ls[threadIdx.x + 192];
        gpart[(size_t)(g * PSPLIT + part) * 64 + threadIdx.x] = v;
    }
}

__global__ void final_kernel(const float* __restrict__ gpart, const int* __restrict__ gstart,
                             float* __restrict__ out) {
    int t = blockIdx.x * blockDim.x + threadIdx.x;
    if (t >= NG * 64) return;
    int g = t >> 6, j = t & 63;
    float s = 0.f;
#pragma unroll
    for (int p = 0; p < PSPLIT; ++p) s += gpart[(size_t)(g * PSPLIT + p) * 64 + j];
    int cnt = gstart[g + 1] - gstart[g];
    out[t] = s / (float)max(cnt, 1);
}

// ---- launch ------------------------------------------------------------
extern "C" void kernel_launch(void* const* d_in, const int* in_sizes, int n_in,
                              void* d_out, int out_size, void* d_ws, size_t ws_size,
                              hipStream_t stream) {
    const float* x     = (const float*)d_in[0];
    const int*   ei    = (const int*)d_in[1];
    const int*   batch = (const int*)d_in[2];
    const float* Wl0 = (const float*)d_in[4];
    const float* Wr0 = (const float*)d_in[5];
    const float* b0  = (const float*)d_in[6];
    const float* Wl1 = (const float*)d_in[7];
    const float* Wr1 = (const float*)d_in[8];
    const float* b1  = (const float*)d_in[9];
    const float* Wl2 = (const float*)d_in[10];
    const float* Wr2 = (const float*)d_in[11];
    const float* b2  = (const float*)d_in[12];

    const int N = NN, E = NE;
    const int* src = ei;
    const int* dst = ei + E;

    const size_t HB = (size_t)NN * 128 * 2;  // 25.6 MB bf16 buffer
    char* ws = (char*)d_ws;
    short* xbf  = (short*)(ws);
    short* hA   = (short*)(ws + HB);
    short* hB   = (short*)(ws + 2 * HB);
    short* bufQ = (short*)(ws + 3 * HB);
    unsigned char* bufP = (unsigned char*)(ws + 4 * HB);  // fp8 [N][128] max
    char* p = ws + 4 * HB + (size_t)NN * 128;
    short* WT0  = (short*)p;        p += 256 * 128 * 2;
    short* WT1  = (short*)p;        p += 256 * 128 * 2;
    short* WT2  = (short*)p;        p += 128 * 128 * 2;
    float* ideg = (float*)p;        p += (size_t)N * 4;
    int* off    = (int*)p;          p += (size_t)(N + 4) * 4;
    int* blockHist = (int*)p;       p += (size_t)NBUK * ABLK * 4 + 16;
    int* bucketTot = (int*)p;       p += 784 * 4;
    int* bucketBase= (int*)p;       p += 784 * 4;
    int* gstart = (int*)p;          p += (NG + 2) * 4;
    float* gpart = (float*)p;       p += (size_t)NG * PSPLIT * 64 * 4;
    int* perm   = (int*)p;          p += (size_t)NPERM * 4;
    int* binned = (int*)p;          p += (size_t)E * 4;
    int* csr    = (int*)p;          p += (size_t)E * 4;

    // fused: histA + x->bf16 + weights->bf16^T + graph boundaries
    hist_setup_kernel<<<ABLK + 6961, 256, 0, stream>>>(
        dst, blockHist, x, xbf, Wl0, Wr0, WT0, Wl1, Wr1, WT1, Wl2, Wr2, WT2,
        batch, gstart, E);
    scanBlk_kernel<<<NBUK, ABLK, 0, stream>>>(blockHist, bucketTot);
    scanTot_kernel<<<1, 1024, 0, stream>>>(bucketTot, bucketBase, off, E);
    binA_kernel<<<ABLK, 256, 0, stream>>>(src, dst, blockHist, bucketBase, binned, E);
    bucketB_kernel<<<NBUK, 256, 0, stream>>>(binned, bucketBase, csr, off, ideg, perm, N);

    const int GB = cdiv(N, 64);

    // Layer 0
    sage_gemm_mfma<128><<<GB, 256, 0, stream>>>(xbf, WT0, b0, bufP, bufQ, N);
    gather_kernel<128, true><<<NPERM * 8 / 256, 256, 0, stream>>>(csr, off, bufP, ideg, bufQ, hA, perm, N);
    // Layer 1
    sage_gemm_mfma<128><<<GB, 256, 0, stream>>>(hA, WT1, b1, bufP, bufQ, N);
    gather_kernel<128, true><<<NPERM * 8 / 256, 256, 0, stream>>>(csr, off, bufP, ideg, bufQ, hB, perm, N);
    // Layer 2 (no relu)
    sage_gemm_mfma<64><<<GB, 256, 0, stream>>>(hB, WT2, b2, bufP, bufQ, N);
    gather_kernel<64, false><<<NPERM * 4 / 256, 256, 0, stream>>>(csr, off, bufP, ideg, bufQ, hA, perm, N);

    // Pool (segmented, atomic-free)
    pool2_kernel<<<NG * PSPLIT, 256, 0, stream>>>((const unsigned short*)hA, gstart, gpart);
    final_kernel<<<16, 256, 0, stream>>>(gpart, gstart, (float*)d_out);
}

// Round 15
// 238.211 us; speedup vs baseline: 1.0630x; 1.0630x over previous
//
#include <hip/hip_runtime.h>
#include <hip/hip_bf16.h>

#define NN 100000
#define NE 1600000
#define NG 64
#define NBUK 782   // cdiv(NN,128)
#define ABLK 512   // binning blocks
#define ACH 3125   // edges per binning block (512*3125 = 1.6M)
#define PSPLIT 8   // pool parts per graph

typedef short short8 __attribute__((ext_vector_type(8)));
typedef float f32x4 __attribute__((ext_vector_type(4)));
typedef float f32x2 __attribute__((ext_vector_type(2)));
typedef unsigned short ushort8v __attribute__((ext_vector_type(8)));
typedef unsigned int uint4v __attribute__((ext_vector_type(4)));
typedef unsigned int uint2v __attribute__((ext_vector_type(2)));

static inline int cdiv(int a, int b) { return (a + b - 1) / b; }

__device__ __forceinline__ short f2bf(float f) {
    return __builtin_bit_cast(short, __float2bfloat16(f));
}
__device__ __forceinline__ float bf2f(unsigned short u) {
    unsigned int x = ((unsigned int)u) << 16;
    return __builtin_bit_cast(float, x);
}

// ---- fused histA + setup (xcvt, wt0/1/2, gbound) -----------------------
__device__ __forceinline__ void wt_body(const float* Wl, const float* Wr, short* WT,
                                        int OUT, int idx) {
    int c = idx >> 7, k = idx & 127;
    float v = (c < OUT) ? Wl[k * OUT + c] : Wr[k * OUT + (c - OUT)];
    WT[idx] = f2bf(v);
}

__global__ __launch_bounds__(256) void hist_setup_kernel(
    const int* __restrict__ dst, int* __restrict__ blockHist,
    const float* __restrict__ x, short* __restrict__ xb,
    const float* __restrict__ Wl0, const float* __restrict__ Wr0, short* __restrict__ WT0,
    const float* __restrict__ Wl1, const float* __restrict__ Wr1, short* __restrict__ WT1,
    const float* __restrict__ Wl2, const float* __restrict__ Wr2, short* __restrict__ WT2,
    const int* __restrict__ batch, int* __restrict__ gstart, int E) {
    __shared__ int h[NBUK];
    int b = blockIdx.x;
    int tid = threadIdx.x;
    if (b < ABLK) {
        for (int i = tid; i < NBUK; i += 256) h[i] = 0;
        __syncthreads();
        int base = b * ACH;
        int end = min(base + ACH, E);
        for (int e = base + tid; e < end; e += 256) atomicAdd(&h[dst[e] >> 7], 1);
        __syncthreads();
        for (int i = tid; i < NBUK; i += 256) blockHist[(size_t)i * ABLK + b] = h[i];
    } else if (b < ABLK + 6250) {
        int i = (b - ABLK) * 256 + tid;  // n8 = 1,600,000
        const float4 v0 = ((const float4*)x)[i * 2];
        const float4 v1 = ((const float4*)x)[i * 2 + 1];
        short8 o;
        o[0] = f2bf(v0.x); o[1] = f2bf(v0.y); o[2] = f2bf(v0.z); o[3] = f2bf(v0.w);
        o[4] = f2bf(v1.x); o[5] = f2bf(v1.y); o[6] = f2bf(v1.z); o[7] = f2bf(v1.w);
        ((short8*)xb)[i] = o;
    } else if (b < ABLK + 6378) {
        wt_body(Wl0, Wr0, WT0, 128, (b - ABLK - 6250) * 256 + tid);
    } else if (b < ABLK + 6506) {
        wt_body(Wl1, Wr1, WT1, 128, (b - ABLK - 6378) * 256 + tid);
    } else if (b < ABLK + 6570) {
        wt_body(Wl2, Wr2, WT2, 64, (b - ABLK - 6506) * 256 + tid);
    } else {
        int n = (b - ABLK - 6570) * 256 + tid;
        if (n >= NN) return;
        int g1 = batch[n];
        if (n == 0) {
            for (int g = 0; g <= g1; ++g) gstart[g] = 0;
        } else {
            int pb = batch[n - 1];
            for (int g = pb + 1; g <= g1; ++g) gstart[g] = n;
        }
        if (n == NN - 1) {
            for (int g = g1 + 1; g <= NG; ++g) gstart[g] = NN;
        }
    }
}

__global__ __launch_bounds__(512) void scanBlk_kernel(int* __restrict__ blockHist,
                                                      int* __restrict__ bucketTot) {
    __shared__ int s[ABLK];
    int b = blockIdx.x, t = threadIdx.x;
    int v = blockHist[(size_t)b * ABLK + t];
    s[t] = v;
    __syncthreads();
    for (int o = 1; o < ABLK; o <<= 1) {
        int u = (t >= o) ? s[t - o] : 0;
        __syncthreads();
        s[t] += u;
        __syncthreads();
    }
    blockHist[(size_t)b * ABLK + t] = s[t] - v;
    if (t == ABLK - 1) bucketTot[b] = s[ABLK - 1];
}

__global__ __launch_bounds__(1024) void scanTot_kernel(const int* __restrict__ bucketTot,
                                                       int* __restrict__ bucketBase,
                                                       int* __restrict__ off, int E) {
    __shared__ int s[1024];
    int t = threadIdx.x;
    int v = (t < NBUK) ? bucketTot[t] : 0;
    s[t] = v;
    __syncthreads();
    for (int o = 1; o < 1024; o <<= 1) {
        int u = (t >= o) ? s[t - o] : 0;
        __syncthreads();
        s[t] += u;
        __syncthreads();
    }
    if (t < NBUK) bucketBase[t] = s[t] - v;
    if (t == 0) {
        bucketBase[NBUK] = E;
        off[NN] = E;
    }
}

__global__ __launch_bounds__(256) void binA_kernel(const int* __restrict__ src,
                                                   const int* __restrict__ dst,
                                                   const int* __restrict__ blockHist,
                                                   const int* __restrict__ bucketBase,
                                                   int* __restrict__ binned, int E) {
    __shared__ int cur[NBUK];
    __shared__ int lbase[NBUK];
    for (int i = threadIdx.x; i < NBUK; i += 256) {
        cur[i] = 0;
        lbase[i] = bucketBase[i] + blockHist[(size_t)i * ABLK + blockIdx.x];
    }
    __syncthreads();
    int base = blockIdx.x * ACH;
    int end = min(base + ACH, E);
    for (int e = base + threadIdx.x; e < end; e += 256) {
        int d = dst[e];
        int b = d >> 7;
        int r = atomicAdd(&cur[b], 1);
        binned[lbase[b] + r] = src[e] | ((d & 127) << 20);
    }
}

// per bucket: single LDS pass (bucket size ~2048 +- 45 whp) -> deg/off/ideg
// + local counting sort -> coalesced csr flush.
__global__ __launch_bounds__(256) void bucketB_kernel(const int* __restrict__ binned,
                                                      const int* __restrict__ bucketBase,
                                                      int* __restrict__ csr,
                                                      int* __restrict__ off,
                                                      float* __restrict__ ideg, int N) {
    __shared__ int pair[4096];
    __shared__ int stage[4096];
    __shared__ int deg[128], loff[128], cur[128];
    int b = blockIdx.x, t = threadIdx.x;
    int e0 = bucketBase[b], e1 = bucketBase[b + 1];
    int cnt = e1 - e0;
    bool fits = (cnt <= 4096);
    if (t < 128) deg[t] = 0;
    __syncthreads();
    if (fits) {
        for (int i = t; i < cnt; i += 256) pair[i] = binned[e0 + i];
        __syncthreads();
        for (int i = t; i < cnt; i += 256) atomicAdd(&deg[pair[i] >> 20], 1);
    } else {
        for (int i = t; i < cnt; i += 256) atomicAdd(&deg[binned[e0 + i] >> 20], 1);
    }
    __syncthreads();
    if (t < 128) loff[t] = deg[t];
    __syncthreads();
    for (int o = 1; o < 128; o <<= 1) {
        int u = (t < 128 && t >= o) ? loff[t - o] : 0;
        __syncthreads();
        if (t < 128) loff[t] += u;
        __syncthreads();
    }
    int nodeBase = b * 128;
    if (t < 128) {
        int ex = loff[t] - deg[t];
        cur[t] = ex;
        int n = nodeBase + t;
        if (n < N) {
            off[n] = e0 + ex;
            ideg[n] = 1.0f / (float)max(deg[t], 1);
        }
    }
    __syncthreads();
    if (fits) {
        for (int i = t; i < cnt; i += 256) {
            int p = pair[i];
            int r = atomicAdd(&cur[p >> 20], 1);
            stage[r] = p & 0xFFFFF;
        }
        __syncthreads();
        for (int i = t; i < cnt; i += 256) csr[e0 + i] = stage[i];
    } else {
        for (int i = t; i < cnt; i += 256) {
            int p = binned[e0 + i];
            int r = atomicAdd(&cur[p >> 20], 1);
            csr[e0 + r] = p & 0xFFFFF;
        }
    }
}

// ---- MFMA dual GEMM: P(fp8) = h@Wl, Q(bf16) = h@Wr + b -----------------
// A-tile LDS-staged once per block via global_load_lds (XOR-swizzled);
// swapped-operand MFMA (D^T) + LDS repack for coalesced vector stores.
template <int OUT>
__global__ __launch_bounds__(256) void sage_gemm_mfma(
    const short* __restrict__ h, const short* __restrict__ WT,
    const float* __restrict__ bias,
    unsigned char* __restrict__ P, short* __restrict__ Q, int N) {
    constexpr int K = 128;
    constexpr int NT = OUT / 32;       // 16-col tiles per wave
    constexpr int WC = OUT / 2;        // cols per wave (64 or 32)
    constexpr int PWP = WC / 4 + 4;    // P LDS pitch in words
    constexpr int PWQ = WC / 2 + 4;    // Q LDS pitch in words
    constexpr int LDSB = 32 * PWQ * 4; // per-wave epilogue LDS bytes

    __shared__ char As[16384];         // 64 rows x 128 bf16, swizzled
    __shared__ char eLds[4 * LDSB];

    const int tid = threadIdx.x;
    const int w = tid >> 6;
    const int lane = tid & 63;
    const int l15 = lane & 15;
    const int lhi = lane >> 4;
    const int rowBase = blockIdx.x * 64;
    const int colBase = w * WC;            // WT row base
    const bool isQ = (w >= 2);
    const int ocolBase = isQ ? colBase - OUT : colBase;
    char* myL = eLds + w * LDSB;

    // stage A tile: dest linear, source inverse-XOR-swizzled so
    // LDS[row][col ^ ((row&7)<<4)] = G[row][col].
    {
        const char* gsrc = (const char*)(h + (size_t)rowBase * K);
#pragma unroll
        for (int p = 0; p < 4; ++p) {
            int lbase = (w * 4 + p) * 1024;
            int loff = lbase + lane * 16;
            int row = loff >> 8;
            int scol = (loff & 255) ^ ((row & 7) << 4);
            __builtin_amdgcn_global_load_lds(
                (const __attribute__((address_space(1))) unsigned int*)(gsrc + (size_t)row * 256 + scol),
                (__attribute__((address_space(3))) unsigned int*)(As + lbase),
                16, 0, 0);
        }
    }
    __syncthreads();

    f32x4 acc[4][NT];
#pragma unroll
    for (int mt = 0; mt < 4; ++mt)
#pragma unroll
        for (int nt = 0; nt < NT; ++nt) acc[mt][nt] = (f32x4){0.f, 0.f, 0.f, 0.f};

#pragma unroll
    for (int kt = 0; kt < 4; ++kt) {
        const int kb = kt * 64 + lhi * 16;  // byte offset within row
        short8 a[4], b[NT];
#pragma unroll
        for (int mt = 0; mt < 4; ++mt) {
            int row = mt * 16 + l15;
            a[mt] = *(const short8*)(As + row * 256 + (kb ^ ((row & 7) << 4)));
        }
#pragma unroll
        for (int nt = 0; nt < NT; ++nt)
            b[nt] = *(const short8*)(WT + (size_t)(colBase + nt * 16 + l15) * K + kt * 32 + lhi * 8);
        // swapped operands -> transposed output tile
#pragma unroll
        for (int mt = 0; mt < 4; ++mt)
#pragma unroll
            for (int nt = 0; nt < NT; ++nt)
                acc[mt][nt] = __builtin_amdgcn_mfma_f32_16x16x32_bf16(b[nt], a[mt], acc[mt][nt], 0, 0, 0);
    }

    if (!isQ) {
        // P: pack 4 fp8 per (mt,nt) -> LDS -> coalesced dwordx4 stores
        constexpr int LPR = WC / 16;
        constexpr int RPP = 64 / LPR;
        constexpr int NP = 32 / RPP;
#pragma unroll
        for (int hh = 0; hh < 2; ++hh) {
#pragma unroll
            for (int mt2 = 0; mt2 < 2; ++mt2) {
                int mt = hh * 2 + mt2;
                int lr = mt2 * 16 + l15;
#pragma unroll
                for (int nt = 0; nt < NT; ++nt) {
                    unsigned u = (unsigned)__builtin_amdgcn_cvt_pk_fp8_f32(
                        acc[mt][nt][0], acc[mt][nt][1], 0, false);
                    u = (unsigned)__builtin_amdgcn_cvt_pk_fp8_f32(
                        acc[mt][nt][2], acc[mt][nt][3], (int)u, true);
                    *(unsigned*)(myL + (size_t)(lr * PWP + nt * 4 + lhi) * 4) = u;
                }
            }
#pragma unroll
            for (int p2 = 0; p2 < NP; ++p2) {
                int lr = p2 * RPP + lane / LPR;
                int wc = (lane % LPR) * 4;
                uint4v v = *(uint4v*)(myL + (size_t)(lr * PWP + wc) * 4);
                int grow = rowBase + hh * 32 + lr;
                if (grow < N)
                    *(uint4v*)(P + (size_t)grow * OUT + ocolBase + wc * 4) = v;
            }
        }
    } else {
        // Q: +bias, pack 4 bf16 (8B) per (mt,nt) -> LDS -> dwordx4 stores
        float4 bj[NT];
#pragma unroll
        for (int nt = 0; nt < NT; ++nt)
            bj[nt] = *(const float4*)(bias + ocolBase + nt * 16 + lhi * 4);
        constexpr int LPR = WC / 8;
        constexpr int RPP = 64 / LPR;
        constexpr int NP = 32 / RPP;
#pragma unroll
        for (int hh = 0; hh < 2; ++hh) {
#pragma unroll
            for (int mt2 = 0; mt2 < 2; ++mt2) {
                int mt = hh * 2 + mt2;
                int lr = mt2 * 16 + l15;
#pragma unroll
                for (int nt = 0; nt < NT; ++nt) {
                    float v0 = acc[mt][nt][0] + bj[nt].x;
                    float v1 = acc[mt][nt][1] + bj[nt].y;
                    float v2 = acc[mt][nt][2] + bj[nt].z;
                    float v3 = acc[mt][nt][3] + bj[nt].w;
                    unsigned lo = ((unsigned)(unsigned short)f2bf(v0)) |
                                  ((unsigned)(unsigned short)f2bf(v1) << 16);
                    unsigned hi = ((unsigned)(unsigned short)f2bf(v2)) |
                                  ((unsigned)(unsigned short)f2bf(v3) << 16);
                    uint2v u; u[0] = lo; u[1] = hi;
                    *(uint2v*)(myL + (size_t)(lr * PWQ + (nt * 4 + lhi) * 2) * 4) = u;
                }
            }
#pragma unroll
            for (int p2 = 0; p2 < NP; ++p2) {
                int lr = p2 * RPP + lane / LPR;
                int wc = (lane % LPR) * 4;
                uint4v v = *(uint4v*)(myL + (size_t)(lr * PWQ + wc) * 4);
                int grow = rowBase + hh * 32 + lr;
                if (grow < N)
                    *(uint4v*)((unsigned short*)Q + (size_t)grow * OUT + ocolBase + (lane % LPR) * 8) = v;
            }
        }
    }
}

// ---- CSR gather: hout[n] = relu?(Q[n] + ideg[n] * sum P[src]) ----------
template <int F, bool RELU>
__global__ __launch_bounds__(256) void gather_kernel(
    const int* __restrict__ csr, const int* __restrict__ off,
    const unsigned char* __restrict__ P, const float* __restrict__ ideg,
    const short* __restrict__ Qin, short* __restrict__ hout, int N) {
    constexpr int C = F / 16;  // threads per node row
    int t = blockIdx.x * blockDim.x + threadIdx.x;
    int n = t / C, c = t % C;
    if (n >= N) return;
    int e0 = off[n], e1 = off[n + 1];
    const size_t cb = (size_t)c * 16;

    float f[16];
#pragma unroll
    for (int j = 0; j < 16; ++j) f[j] = 0.f;

    int e = e0;
    for (; e + 4 <= e1; e += 4) {
        int s0 = csr[e + 0], s1 = csr[e + 1], s2 = csr[e + 2], s3 = csr[e + 3];
        uint4v u0 = *(const uint4v*)(P + (size_t)s0 * F + cb);
        uint4v u1 = *(const uint4v*)(P + (size_t)s1 * F + cb);
        uint4v u2 = *(const uint4v*)(P + (size_t)s2 * F + cb);
        uint4v u3 = *(const uint4v*)(P + (size_t)s3 * F + cb);
#pragma unroll
        for (int wd = 0; wd < 4; ++wd) {
            f32x2 a0 = __builtin_amdgcn_cvt_pk_f32_fp8(u0[wd], false);
            f32x2 b0 = __builtin_amdgcn_cvt_pk_f32_fp8(u0[wd], true);
            f32x2 a1 = __builtin_amdgcn_cvt_pk_f32_fp8(u1[wd], false);
            f32x2 b1 = __builtin_amdgcn_cvt_pk_f32_fp8(u1[wd], true);
            f32x2 a2 = __builtin_amdgcn_cvt_pk_f32_fp8(u2[wd], false);
            f32x2 b2 = __builtin_amdgcn_cvt_pk_f32_fp8(u2[wd], true);
            f32x2 a3 = __builtin_amdgcn_cvt_pk_f32_fp8(u3[wd], false);
            f32x2 b3 = __builtin_amdgcn_cvt_pk_f32_fp8(u3[wd], true);
            f[wd * 4 + 0] += (a0[0] + a1[0]) + (a2[0] + a3[0]);
            f[wd * 4 + 1] += (a0[1] + a1[1]) + (a2[1] + a3[1]);
            f[wd * 4 + 2] += (b0[0] + b1[0]) + (b2[0] + b3[0]);
            f[wd * 4 + 3] += (b0[1] + b1[1]) + (b2[1] + b3[1]);
        }
    }
    for (; e < e1; ++e) {
        uint4v u = *(const uint4v*)(P + (size_t)csr[e] * F + cb);
#pragma unroll
        for (int wd = 0; wd < 4; ++wd) {
            f32x2 a = __builtin_amdgcn_cvt_pk_f32_fp8(u[wd], false);
            f32x2 b = __builtin_amdgcn_cvt_pk_f32_fp8(u[wd], true);
            f[wd * 4 + 0] += a[0];
            f[wd * 4 + 1] += a[1];
            f[wd * 4 + 2] += b[0];
            f[wd * 4 + 3] += b[1];
        }
    }

    float sc = ideg[n];
    const short* qp = Qin + (size_t)n * F + cb;
    ushort8v qa = *(const ushort8v*)qp, qb = *(const ushort8v*)(qp + 8);
    short8 oa, ob;
#pragma unroll
    for (int j = 0; j < 8; ++j) {
        float va = fmaf(f[j], sc, bf2f(qa[j]));
        float vb = fmaf(f[j + 8], sc, bf2f(qb[j]));
        if (RELU) { va = fmaxf(va, 0.f); vb = fmaxf(vb, 0.f); }
        oa[j] = f2bf(va);
        ob[j] = f2bf(vb);
    }
    short* op = hout + (size_t)n * F + cb;
    *(short8*)op = oa;
    *(short8*)(op + 8) = ob;
}

// ---- segmented mean pool: 8 parts per graph, no atomics -----------------
__global__ __launch_bounds__(256) void pool2_kernel(const unsigned short* __restrict__ h,
                                                    const int* __restrict__ gstart,
                                                    float* __restrict__ gpart) {
    int g = blockIdx.x / PSPLIT, part = blockIdx.x % PSPLIT;
    int s = gstart[g], e = gstart[g + 1];
    int cnt = e - s;
    int chunk = (cnt + PSPLIT - 1) / PSPLIT;
    int n0 = s + part * chunk;
    int n1 = min(n0 + chunk, e);
    int j = threadIdx.x & 63;
    int r = threadIdx.x >> 6;  // 4 row lanes
    float acc = 0.f;
    for (int n = n0 + r; n < n1; n += 4) acc += bf2f(h[(size_t)n * 64 + j]);
    __shared__ float ls[256];
    ls[threadIdx.x] = acc;
    __syncthreads();
    if (threadIdx.x < 64) {
        float v = ls[threadIdx.x] + ls[threadIdx.x + 64] + ls[threadIdx.x + 128] + ls[threadIdx.x + 192];
        gpart[(size_t)(g * PSPLIT + part) * 64 + threadIdx.x] = v;
    }
}

__global__ void final_kernel(const float* __restrict__ gpart, const int* __restrict__ gstart,
                             float* __restrict__ out) {
    int t = blockIdx.x * blockDim.x + threadIdx.x;
    if (t >= NG * 64) return;
    int g = t >> 6, j = t & 63;
    float s = 0.f;
#pragma unroll
    for (int p = 0; p < PSPLIT; ++p) s += gpart[(size_t)(g * PSPLIT + p) * 64 + j];
    int cnt = gstart[g + 1] - gstart[g];
    out[t] = s / (float)max(cnt, 1);
}

// ---- launch ------------------------------------------------------------
extern "C" void kernel_launch(void* const* d_in, const int* in_sizes, int n_in,
                              void* d_out, int out_size, void* d_ws, size_t ws_size,
                              hipStream_t stream) {
    const float* x     = (const float*)d_in[0];
    const int*   ei    = (const int*)d_in[1];
    const int*   batch = (const int*)d_in[2];
    const float* Wl0 = (const float*)d_in[4];
    const float* Wr0 = (const float*)d_in[5];
    const float* b0  = (const float*)d_in[6];
    const float* Wl1 = (const float*)d_in[7];
    const float* Wr1 = (const float*)d_in[8];
    const float* b1  = (const float*)d_in[9];
    const float* Wl2 = (const float*)d_in[10];
    const float* Wr2 = (const float*)d_in[11];
    const float* b2  = (const float*)d_in[12];

    const int N = NN, E = NE;
    const int* src = ei;
    const int* dst = ei + E;

    const size_t HB = (size_t)NN * 128 * 2;  // 25.6 MB bf16 buffer
    char* ws = (char*)d_ws;
    short* xbf  = (short*)(ws);
    short* hA   = (short*)(ws + HB);
    short* hB   = (short*)(ws + 2 * HB);
    short* bufQ = (short*)(ws + 3 * HB);
    unsigned char* bufP = (unsigned char*)(ws + 4 * HB);  // fp8 [N][128] max
    char* p = ws + 4 * HB + (size_t)NN * 128;
    short* WT0  = (short*)p;        p += 256 * 128 * 2;
    short* WT1  = (short*)p;        p += 256 * 128 * 2;
    short* WT2  = (short*)p;        p += 128 * 128 * 2;
    float* ideg = (float*)p;        p += (size_t)N * 4;
    int* off    = (int*)p;          p += (size_t)(N + 4) * 4;
    int* blockHist = (int*)p;       p += (size_t)NBUK * ABLK * 4 + 16;
    int* bucketTot = (int*)p;       p += 784 * 4;
    int* bucketBase= (int*)p;       p += 784 * 4;
    int* gstart = (int*)p;          p += (NG + 2) * 4;
    float* gpart = (float*)p;       p += (size_t)NG * PSPLIT * 64 * 4;
    int* binned = (int*)p;          p += (size_t)E * 4;
    int* csr    = (int*)p;          p += (size_t)E * 4;

    // fused: histA + x->bf16 + weights->bf16^T + graph boundaries
    hist_setup_kernel<<<ABLK + 6961, 256, 0, stream>>>(
        dst, blockHist, x, xbf, Wl0, Wr0, WT0, Wl1, Wr1, WT1, Wl2, Wr2, WT2,
        batch, gstart, E);
    scanBlk_kernel<<<NBUK, ABLK, 0, stream>>>(blockHist, bucketTot);
    scanTot_kernel<<<1, 1024, 0, stream>>>(bucketTot, bucketBase, off, E);
    binA_kernel<<<ABLK, 256, 0, stream>>>(src, dst, blockHist, bucketBase, binned, E);
    bucketB_kernel<<<NBUK, 256, 0, stream>>>(binned, bucketBase, csr, off, ideg, N);

    const int GB = cdiv(N, 64);

    // Layer 0
    sage_gemm_mfma<128><<<GB, 256, 0, stream>>>(xbf, WT0, b0, bufP, bufQ, N);
    gather_kernel<128, true><<<cdiv(N * 8, 256), 256, 0, stream>>>(csr, off, bufP, ideg, bufQ, hA, N);
    // Layer 1
    sage_gemm_mfma<128><<<GB, 256, 0, stream>>>(hA, WT1, b1, bufP, bufQ, N);
    gather_kernel<128, true><<<cdiv(N * 8, 256), 256, 0, stream>>>(csr, off, bufP, ideg, bufQ, hB, N);
    // Layer 2 (no relu)
    sage_gemm_mfma<64><<<GB, 256, 0, stream>>>(hB, WT2, b2, bufP, bufQ, N);
    gather_kernel<64, false><<<cdiv(N * 4, 256), 256, 0, stream>>>(csr, off, bufP, ideg, bufQ, hA, N);

    // Pool (segmented, atomic-free)
    pool2_kernel<<<NG * PSPLIT, 256, 0, stream>>>((const unsigned short*)hA, gstart, gpart);
    final_kernel<<<16, 256, 0, stream>>>(gpart, gstart, (float*)d_out);
}